// Round 1
// baseline (2021.274 us; speedup 1.0000x reference)
//
#include <hip/hip_runtime.h>
#include <cmath>

// Problem constants (from reference setup_inputs)
constexpr int Bdim = 64;
constexpr int Fdim = 4096;
constexpr int Edim = 256;
constexpr int Hdim = 512;
constexpr int Udim = 512;

// Score kernel tiling
constexpr int TFt = 64;            // f-tile per block
constexpr int TUt = 64;            // u-chunk per iteration
constexpr int LDR = Edim + 4;      // 260 floats: keeps 16B alignment, bank stride 4

// ---------------------------------------------------------------------------
// Kernel 1: c[b][u] = W1_b[u] + W2_b[u] + sum_h hidden[b,h] * W2_w[h,u]
// ---------------------------------------------------------------------------
__global__ __launch_bounds__(256) void proj_h_kernel(
    const float* __restrict__ hidden, const float* __restrict__ W2,
    const float* __restrict__ W1b, const float* __restrict__ W2b,
    float* __restrict__ cb)
{
    const int b = blockIdx.x;
    const int tid = threadIdx.x;
    const float* hb = hidden + (size_t)b * Hdim;
    for (int u = tid; u < Udim; u += 256) {
        float acc = 0.f;
        #pragma unroll 8
        for (int h = 0; h < Hdim; ++h)
            acc = fmaf(hb[h], W2[(size_t)h * Udim + u], acc);
        cb[(size_t)b * Udim + u] = acc + W1b[u] + W2b[u];
    }
}

// ---------------------------------------------------------------------------
// Kernel 2 (dominant): scores[b][f] = Vb + sum_u tanh(feat[b,f,:].W1[:,u] + c[b,u]) * Vw[u]
// 64f x 64u block tile, 256 threads, 4x4 register tile, fp32 FMA.
// LDS: feat tile [64][260] + W1 chunk transposed [64][260] = 133,120 B (1 block/CU).
// ---------------------------------------------------------------------------
__global__ __launch_bounds__(256) void score_kernel(
    const float* __restrict__ feat, const float* __restrict__ W1,
    const float* __restrict__ Vw, const float* __restrict__ Vb,
    const float* __restrict__ cb, float* __restrict__ scores)
{
    __shared__ float sA[TFt * LDR];
    __shared__ float sW[TUt * LDR];

    const int b   = blockIdx.y;
    const int f0  = blockIdx.x * TFt;
    const int tid = threadIdx.x;
    const int tf  = tid >> 4;   // 0..15
    const int tu  = tid & 15;   // 0..15

    // Stage features tile: 64 rows x 256 floats, fully coalesced float4 loads.
    {
        const float4* gA = (const float4*)(feat + ((size_t)b * Fdim + f0) * Edim);
        #pragma unroll
        for (int it = 0; it < 16; ++it) {
            const int i = tid + it * 256;        // 0..4095
            const int f = i >> 6;                // row
            const int q = i & 63;                // float4 within row
            const float4 v = gA[i];
            *(float4*)&sA[f * LDR + 4 * q] = v;
        }
    }

    float sacc[4] = {0.f, 0.f, 0.f, 0.f};
    const float* cbb = cb + (size_t)b * Udim;

    for (int uc = 0; uc < Udim; uc += TUt) {
        __syncthreads();   // protect previous sW consumers
        // Stage W1 chunk transposed: sW[u][e] = W1[e][uc+u]
        #pragma unroll
        for (int it = 0; it < 16; ++it) {
            const int i = tid + it * 256;        // 0..4095
            const int e = i >> 4;                // 0..255
            const int q = i & 15;                // u-quad
            const float4 v = *(const float4*)(W1 + (size_t)e * Udim + uc + 4 * q);
            sW[(4 * q + 0) * LDR + e] = v.x;
            sW[(4 * q + 1) * LDR + e] = v.y;
            sW[(4 * q + 2) * LDR + e] = v.z;
            sW[(4 * q + 3) * LDR + e] = v.w;
        }
        __syncthreads();

        float acc[4][4] = {};
        #pragma unroll 4
        for (int e = 0; e < Edim; e += 4) {
            float4 a0 = *(const float4*)&sA[(tf +  0) * LDR + e];
            float4 a1 = *(const float4*)&sA[(tf + 16) * LDR + e];
            float4 a2 = *(const float4*)&sA[(tf + 32) * LDR + e];
            float4 a3 = *(const float4*)&sA[(tf + 48) * LDR + e];
            float4 w0 = *(const float4*)&sW[(tu +  0) * LDR + e];
            float4 w1 = *(const float4*)&sW[(tu + 16) * LDR + e];
            float4 w2 = *(const float4*)&sW[(tu + 32) * LDR + e];
            float4 w3 = *(const float4*)&sW[(tu + 48) * LDR + e];
            #define FMA4(i, j, A, W)                         \
                acc[i][j] = fmaf(A.x, W.x, acc[i][j]);       \
                acc[i][j] = fmaf(A.y, W.y, acc[i][j]);       \
                acc[i][j] = fmaf(A.z, W.z, acc[i][j]);       \
                acc[i][j] = fmaf(A.w, W.w, acc[i][j]);
            FMA4(0,0,a0,w0) FMA4(0,1,a0,w1) FMA4(0,2,a0,w2) FMA4(0,3,a0,w3)
            FMA4(1,0,a1,w0) FMA4(1,1,a1,w1) FMA4(1,2,a1,w2) FMA4(1,3,a1,w3)
            FMA4(2,0,a2,w0) FMA4(2,1,a2,w1) FMA4(2,2,a2,w2) FMA4(2,3,a2,w3)
            FMA4(3,0,a3,w0) FMA4(3,1,a3,w1) FMA4(3,2,a3,w2) FMA4(3,3,a3,w3)
            #undef FMA4
        }

        // Epilogue for this u-chunk: tanh + dot with V_w
        #pragma unroll
        for (int j = 0; j < 4; ++j) {
            const int u = uc + tu + 16 * j;
            const float vw = Vw[u];
            const float cu = cbb[u];
            #pragma unroll
            for (int i = 0; i < 4; ++i)
                sacc[i] = fmaf(tanhf(acc[i][j] + cu), vw, sacc[i]);
        }
    }

    // Reduce over tu (16 lanes, bits 0..3 of lane id), then write 4 scores.
    const float vb = Vb[0];
    #pragma unroll
    for (int i = 0; i < 4; ++i) {
        float s = sacc[i];
        s += __shfl_xor(s, 1);
        s += __shfl_xor(s, 2);
        s += __shfl_xor(s, 4);
        s += __shfl_xor(s, 8);
        if (tu == 0)
            scores[(size_t)b * Fdim + f0 + tf + 16 * i] = s + vb;
    }
}

// ---------------------------------------------------------------------------
// Kernel 3: in-place softmax over F for each b (scores -> weights)
// ---------------------------------------------------------------------------
__global__ __launch_bounds__(256) void softmax_kernel(float* __restrict__ sc)
{
    __shared__ float red[256];
    const int b = blockIdx.x;
    const int tid = threadIdx.x;
    float* row = sc + (size_t)b * Fdim;

    float v[16];
    float m = -INFINITY;
    #pragma unroll
    for (int i = 0; i < 16; ++i) {
        v[i] = row[tid + 256 * i];
        m = fmaxf(m, v[i]);
    }
    red[tid] = m;
    __syncthreads();
    for (int s = 128; s > 0; s >>= 1) {
        if (tid < s) red[tid] = fmaxf(red[tid], red[tid + s]);
        __syncthreads();
    }
    m = red[0];
    __syncthreads();

    float sum = 0.f;
    #pragma unroll
    for (int i = 0; i < 16; ++i) {
        v[i] = expf(v[i] - m);
        sum += v[i];
    }
    red[tid] = sum;
    __syncthreads();
    for (int s = 128; s > 0; s >>= 1) {
        if (tid < s) red[tid] += red[tid + s];
        __syncthreads();
    }
    const float inv = 1.f / red[0];
    #pragma unroll
    for (int i = 0; i < 16; ++i)
        row[tid + 256 * i] = v[i] * inv;
}

// ---------------------------------------------------------------------------
// Kernel 4: context[b][e] = sum_f weights[b][f] * feat[b][f][e]
// Split F into 16 chunks of 256 for parallelism; atomicAdd partials.
// ---------------------------------------------------------------------------
__global__ __launch_bounds__(256) void context_kernel(
    const float* __restrict__ feat, const float* __restrict__ wts,
    float* __restrict__ ctx)
{
    const int b  = blockIdx.y;       // 64
    const int fc = blockIdx.x;       // 16 chunks of 256 f
    const int e  = threadIdx.x;      // 256

    const float* fp = feat + ((size_t)b * Fdim + (size_t)fc * 256) * Edim + e;
    const float* wp = wts + (size_t)b * Fdim + (size_t)fc * 256;

    float acc = 0.f;
    #pragma unroll 8
    for (int f = 0; f < 256; ++f)
        acc = fmaf(wp[f], fp[(size_t)f * Edim], acc);

    atomicAdd(&ctx[(size_t)b * Edim + e], acc);
}

// ---------------------------------------------------------------------------
extern "C" void kernel_launch(void* const* d_in, const int* in_sizes, int n_in,
                              void* d_out, int out_size, void* d_ws, size_t ws_size,
                              hipStream_t stream)
{
    const float* features = (const float*)d_in[0];   // (B,F,E)
    const float* hidden   = (const float*)d_in[1];   // (B,H)
    const float* W1w      = (const float*)d_in[2];   // (E,U)
    const float* W1b      = (const float*)d_in[3];   // (U,)
    const float* W2w      = (const float*)d_in[4];   // (H,U)
    const float* W2b      = (const float*)d_in[5];   // (U,)
    const float* Vw       = (const float*)d_in[6];   // (U,1)
    const float* Vb       = (const float*)d_in[7];   // (1,)

    float* ctx = (float*)d_out;                      // (B,E) = 16384 floats
    float* wts = (float*)d_out + (size_t)Bdim * Edim; // (B,F) = 262144 floats
    float* cb  = (float*)d_ws;                       // (B,U) scratch, 128 KiB

    // Zero the context accumulator region (d_out is poisoned before each call).
    hipMemsetAsync(ctx, 0, (size_t)Bdim * Edim * sizeof(float), stream);

    proj_h_kernel<<<Bdim, 256, 0, stream>>>(hidden, W2w, W1b, W2b, cb);

    dim3 sgrid(Fdim / TFt, Bdim);   // (64, 64)
    score_kernel<<<sgrid, 256, 0, stream>>>(features, W1w, Vw, Vb, cb, wts);

    softmax_kernel<<<Bdim, 256, 0, stream>>>(wts);

    dim3 cgrid(16, Bdim);
    context_kernel<<<cgrid, 256, 0, stream>>>(features, wts, ctx);
}

// Round 2
// 689.842 us; speedup vs baseline: 2.9301x; 2.9301x over previous
//
#include <hip/hip_runtime.h>
#include <cmath>

// Problem constants (from reference setup_inputs)
constexpr int Bdim = 64;
constexpr int Fdim = 4096;
constexpr int Edim = 256;
constexpr int Hdim = 512;
constexpr int Udim = 512;

typedef __attribute__((ext_vector_type(8))) short short8;   // 8 bf16 fragment
typedef __attribute__((ext_vector_type(4))) float f32x4;

// ---------------------------------------------------------------------------
// Helpers: fp32 <-> bf16 (RNE), fast tanh
// ---------------------------------------------------------------------------
__device__ __forceinline__ unsigned short f2bf(float f) {
    unsigned int u = __float_as_uint(f);
    u += 0x7FFFu + ((u >> 16) & 1u);   // round-to-nearest-even (inputs are finite)
    return (unsigned short)(u >> 16);
}
__device__ __forceinline__ float bf2f(unsigned short h) {
    return __uint_as_float(((unsigned int)h) << 16);
}
__device__ __forceinline__ unsigned int pack2(float lo, float hi) {
    return (unsigned int)f2bf(lo) | ((unsigned int)f2bf(hi) << 16);
}
__device__ __forceinline__ float tanh_fast(float x) {
    // tanh(x) = 1 - 2/(1+e^{2x});  handles +-inf limits correctly
    float e = __expf(2.0f * x);
    return 1.0f - 2.0f * __builtin_amdgcn_rcpf(e + 1.0f);
}

// ---------------------------------------------------------------------------
// Kernel 1: c[b][u] = W1_b[u] + W2_b[u] + sum_h hidden[b,h] * W2_w[h,u]
// ---------------------------------------------------------------------------
__global__ __launch_bounds__(256) void proj_h_kernel(
    const float* __restrict__ hidden, const float* __restrict__ W2,
    const float* __restrict__ W1b, const float* __restrict__ W2b,
    float* __restrict__ cb)
{
    const int b = blockIdx.x;
    const int tid = threadIdx.x;
    const float* hb = hidden + (size_t)b * Hdim;
    for (int u = tid; u < Udim; u += 256) {
        float acc = 0.f;
        #pragma unroll 8
        for (int h = 0; h < Hdim; ++h)
            acc = fmaf(hb[h], W2[(size_t)h * Udim + u], acc);
        cb[(size_t)b * Udim + u] = acc + W1b[u] + W2b[u];
    }
}

// ---------------------------------------------------------------------------
// Prep A: features fp32 -> bf16 (rounded), same [b][f][e] layout
// ---------------------------------------------------------------------------
__global__ __launch_bounds__(256) void feat2bf_kernel(
    const float* __restrict__ in, unsigned short* __restrict__ out, long n)
{
    long i = ((long)blockIdx.x * 256 + threadIdx.x) * 8;
    const long stride = (long)gridDim.x * 256 * 8;
    for (; i < n; i += stride) {
        float4 a = *(const float4*)(in + i);
        float4 b = *(const float4*)(in + i + 4);
        uint4 o;
        o.x = pack2(a.x, a.y);
        o.y = pack2(a.z, a.w);
        o.z = pack2(b.x, b.y);
        o.w = pack2(b.z, b.w);
        *(uint4*)(out + i) = o;
    }
}

// ---------------------------------------------------------------------------
// Prep B: W1 (E,U) fp32 -> transposed hi/lo bf16 [U][E]
// ---------------------------------------------------------------------------
__global__ __launch_bounds__(256) void w1t_kernel(
    const float* __restrict__ W1, unsigned short* __restrict__ Th,
    unsigned short* __restrict__ Tl)
{
    const int e = blockIdx.x;                 // 256
    for (int u = threadIdx.x; u < Udim; u += 256) {
        float v = W1[(size_t)e * Udim + u];
        unsigned short h = f2bf(v);
        float lo = v - bf2f(h);
        Th[(size_t)u * Edim + e] = h;
        Tl[(size_t)u * Edim + e] = f2bf(lo);
    }
}

// ---------------------------------------------------------------------------
// Init scores with V_b
// ---------------------------------------------------------------------------
__global__ __launch_bounds__(256) void init_scores_kernel(
    float* __restrict__ sc, const float* __restrict__ Vb)
{
    sc[(size_t)blockIdx.x * 256 + threadIdx.x] = Vb[0];
}

// ---------------------------------------------------------------------------
// Kernel 2 (dominant, MFMA): partial scores via bf16 MFMA GEMM + fused
// tanh/V-dot epilogue.  C[f,u] = feat_bf16[f,:].(W1h + W1l)[:,u]
// Block tile 128f x 128u, BK=32, 4 waves (64x64 each, 4x4 subtiles of 16x16).
// ---------------------------------------------------------------------------
constexpr int LDK = 40;                 // 32 + 8 pad (ushorts per LDS row)

__global__ __launch_bounds__(256) void score_mfma_kernel(
    const unsigned short* __restrict__ featB,  // [B][F][E] bf16
    const unsigned short* __restrict__ W1Th,   // [U][E] bf16 hi
    const unsigned short* __restrict__ W1Tl,   // [U][E] bf16 lo
    const float* __restrict__ Vw, const float* __restrict__ cb,
    float* __restrict__ scores)
{
    __shared__ unsigned short sA[128 * LDK];
    __shared__ unsigned short sBh[128 * LDK];
    __shared__ unsigned short sBl[128 * LDK];

    const int b   = blockIdx.z;
    const int f0  = blockIdx.x * 128;
    const int u0  = blockIdx.y * 128;
    const int tid = threadIdx.x;
    const int lane = tid & 63;
    const int w    = tid >> 6;
    const int wm   = (w & 1) * 64;      // f-offset of wave tile
    const int wn   = (w >> 1) * 64;     // u-offset of wave tile

    const unsigned short* gA  = featB + ((size_t)b * Fdim + f0) * Edim;
    const unsigned short* gBh = W1Th + (size_t)u0 * Edim;
    const unsigned short* gBl = W1Tl + (size_t)u0 * Edim;

    // staging map: thread -> row sr (0..127), 16B chunk at col sc and sc+16
    const int sr = tid >> 1;
    const int sc = (tid & 1) * 8;

    f32x4 acc[4][4] = {};

    for (int k0 = 0; k0 < Edim; k0 += 32) {
        __syncthreads();
        *(uint4*)&sA [sr * LDK + sc]      = *(const uint4*)&gA [(size_t)sr * Edim + k0 + sc];
        *(uint4*)&sA [sr * LDK + sc + 16] = *(const uint4*)&gA [(size_t)sr * Edim + k0 + sc + 16];
        *(uint4*)&sBh[sr * LDK + sc]      = *(const uint4*)&gBh[(size_t)sr * Edim + k0 + sc];
        *(uint4*)&sBh[sr * LDK + sc + 16] = *(const uint4*)&gBh[(size_t)sr * Edim + k0 + sc + 16];
        *(uint4*)&sBl[sr * LDK + sc]      = *(const uint4*)&gBl[(size_t)sr * Edim + k0 + sc];
        *(uint4*)&sBl[sr * LDK + sc + 16] = *(const uint4*)&gBl[(size_t)sr * Edim + k0 + sc + 16];
        __syncthreads();

        const int mrow = lane & 15;
        const int kg   = (lane >> 4) * 8;
        short8 af[4], bh[4], bl[4];
        #pragma unroll
        for (int i = 0; i < 4; ++i) {
            af[i] = *(const short8*)&sA [(wm + i * 16 + mrow) * LDK + kg];
            bh[i] = *(const short8*)&sBh[(wn + i * 16 + mrow) * LDK + kg];
            bl[i] = *(const short8*)&sBl[(wn + i * 16 + mrow) * LDK + kg];
        }
        #pragma unroll
        for (int mi = 0; mi < 4; ++mi)
            #pragma unroll
            for (int nj = 0; nj < 4; ++nj) {
                acc[mi][nj] = __builtin_amdgcn_mfma_f32_16x16x32_bf16(
                    af[mi], bh[nj], acc[mi][nj], 0, 0, 0);
                acc[mi][nj] = __builtin_amdgcn_mfma_f32_16x16x32_bf16(
                    af[mi], bl[nj], acc[mi][nj], 0, 0, 0);
            }
    }

    // Epilogue: tanh + V-dot, reduce over u, atomicAdd partial into scores.
    const int ln15 = lane & 15, q = lane >> 4;
    float cu[4], vv[4];
    #pragma unroll
    for (int nj = 0; nj < 4; ++nj) {
        const int u = u0 + wn + nj * 16 + ln15;
        cu[nj] = cb[(size_t)b * Udim + u];
        vv[nj] = Vw[u];
    }
    #pragma unroll
    for (int mi = 0; mi < 4; ++mi) {
        #pragma unroll
        for (int r = 0; r < 4; ++r) {
            float p = 0.f;
            #pragma unroll
            for (int nj = 0; nj < 4; ++nj)
                p += tanh_fast(acc[mi][nj][r] + cu[nj]) * vv[nj];
            p += __shfl_xor(p, 1);
            p += __shfl_xor(p, 2);
            p += __shfl_xor(p, 4);
            p += __shfl_xor(p, 8);
            if (ln15 == 0) {
                const int f = f0 + wm + mi * 16 + q * 4 + r;
                atomicAdd(&scores[(size_t)b * Fdim + f], p);
            }
        }
    }
}

// ---------------------------------------------------------------------------
// Fallback fp32 score kernel (round-1) — used only if ws too small
// ---------------------------------------------------------------------------
constexpr int TFt = 64;
constexpr int TUt = 64;
constexpr int LDR = Edim + 4;

__global__ __launch_bounds__(256) void score_kernel(
    const float* __restrict__ feat, const float* __restrict__ W1,
    const float* __restrict__ Vw, const float* __restrict__ Vb,
    const float* __restrict__ cb, float* __restrict__ scores)
{
    __shared__ float sA[TFt * LDR];
    __shared__ float sW[TUt * LDR];

    const int b   = blockIdx.y;
    const int f0  = blockIdx.x * TFt;
    const int tid = threadIdx.x;
    const int tf  = tid >> 4;
    const int tu  = tid & 15;

    {
        const float4* gA = (const float4*)(feat + ((size_t)b * Fdim + f0) * Edim);
        #pragma unroll
        for (int it = 0; it < 16; ++it) {
            const int i = tid + it * 256;
            const int f = i >> 6;
            const int qq = i & 63;
            const float4 v = gA[i];
            *(float4*)&sA[f * LDR + 4 * qq] = v;
        }
    }

    float sacc[4] = {0.f, 0.f, 0.f, 0.f};
    const float* cbb = cb + (size_t)b * Udim;

    for (int uc = 0; uc < Udim; uc += TUt) {
        __syncthreads();
        #pragma unroll
        for (int it = 0; it < 16; ++it) {
            const int i = tid + it * 256;
            const int e = i >> 4;
            const int qq = i & 15;
            const float4 v = *(const float4*)(W1 + (size_t)e * Udim + uc + 4 * qq);
            sW[(4 * qq + 0) * LDR + e] = v.x;
            sW[(4 * qq + 1) * LDR + e] = v.y;
            sW[(4 * qq + 2) * LDR + e] = v.z;
            sW[(4 * qq + 3) * LDR + e] = v.w;
        }
        __syncthreads();

        float acc[4][4] = {};
        #pragma unroll 4
        for (int e = 0; e < Edim; e += 4) {
            float4 a0 = *(const float4*)&sA[(tf +  0) * LDR + e];
            float4 a1 = *(const float4*)&sA[(tf + 16) * LDR + e];
            float4 a2 = *(const float4*)&sA[(tf + 32) * LDR + e];
            float4 a3 = *(const float4*)&sA[(tf + 48) * LDR + e];
            float4 w0 = *(const float4*)&sW[(tu +  0) * LDR + e];
            float4 w1 = *(const float4*)&sW[(tu + 16) * LDR + e];
            float4 w2 = *(const float4*)&sW[(tu + 32) * LDR + e];
            float4 w3 = *(const float4*)&sW[(tu + 48) * LDR + e];
            #define FMA4(i, j, A, W)                         \
                acc[i][j] = fmaf(A.x, W.x, acc[i][j]);       \
                acc[i][j] = fmaf(A.y, W.y, acc[i][j]);       \
                acc[i][j] = fmaf(A.z, W.z, acc[i][j]);       \
                acc[i][j] = fmaf(A.w, W.w, acc[i][j]);
            FMA4(0,0,a0,w0) FMA4(0,1,a0,w1) FMA4(0,2,a0,w2) FMA4(0,3,a0,w3)
            FMA4(1,0,a1,w0) FMA4(1,1,a1,w1) FMA4(1,2,a1,w2) FMA4(1,3,a1,w3)
            FMA4(2,0,a2,w0) FMA4(2,1,a2,w1) FMA4(2,2,a2,w2) FMA4(2,3,a2,w3)
            FMA4(3,0,a3,w0) FMA4(3,1,a3,w1) FMA4(3,2,a3,w2) FMA4(3,3,a3,w3)
            #undef FMA4
        }

        #pragma unroll
        for (int j = 0; j < 4; ++j) {
            const int u = uc + tu + 16 * j;
            const float vw = Vw[u];
            const float cuv = cbb[u];
            #pragma unroll
            for (int i = 0; i < 4; ++i)
                sacc[i] = fmaf(tanhf(acc[i][j] + cuv), vw, sacc[i]);
        }
    }

    const float vb = Vb[0];
    #pragma unroll
    for (int i = 0; i < 4; ++i) {
        float s = sacc[i];
        s += __shfl_xor(s, 1);
        s += __shfl_xor(s, 2);
        s += __shfl_xor(s, 4);
        s += __shfl_xor(s, 8);
        if (tu == 0)
            scores[(size_t)b * Fdim + f0 + tf + 16 * i] = s + vb;
    }
}

// ---------------------------------------------------------------------------
// Kernel 3: in-place softmax over F for each b
// ---------------------------------------------------------------------------
__global__ __launch_bounds__(256) void softmax_kernel(float* __restrict__ sc)
{
    __shared__ float red[256];
    const int b = blockIdx.x;
    const int tid = threadIdx.x;
    float* row = sc + (size_t)b * Fdim;

    float v[16];
    float m = -INFINITY;
    #pragma unroll
    for (int i = 0; i < 16; ++i) {
        v[i] = row[tid + 256 * i];
        m = fmaxf(m, v[i]);
    }
    red[tid] = m;
    __syncthreads();
    for (int s = 128; s > 0; s >>= 1) {
        if (tid < s) red[tid] = fmaxf(red[tid], red[tid + s]);
        __syncthreads();
    }
    m = red[0];
    __syncthreads();

    float sum = 0.f;
    #pragma unroll
    for (int i = 0; i < 16; ++i) {
        v[i] = expf(v[i] - m);
        sum += v[i];
    }
    red[tid] = sum;
    __syncthreads();
    for (int s = 128; s > 0; s >>= 1) {
        if (tid < s) red[tid] += red[tid + s];
        __syncthreads();
    }
    const float inv = 1.f / red[0];
    #pragma unroll
    for (int i = 0; i < 16; ++i)
        row[tid + 256 * i] = v[i] * inv;
}

// ---------------------------------------------------------------------------
// Kernel 4: context[b][e] = sum_f weights[b][f] * feat[b][f][e]
// ---------------------------------------------------------------------------
__global__ __launch_bounds__(256) void context_kernel(
    const float* __restrict__ feat, const float* __restrict__ wts,
    float* __restrict__ ctx)
{
    const int b  = blockIdx.y;
    const int fc = blockIdx.x;
    const int e  = threadIdx.x;

    const float* fp = feat + ((size_t)b * Fdim + (size_t)fc * 256) * Edim + e;
    const float* wp = wts + (size_t)b * Fdim + (size_t)fc * 256;

    float acc = 0.f;
    #pragma unroll 8
    for (int f = 0; f < 256; ++f)
        acc = fmaf(wp[f], fp[(size_t)f * Edim], acc);

    atomicAdd(&ctx[(size_t)b * Edim + e], acc);
}

// ---------------------------------------------------------------------------
extern "C" void kernel_launch(void* const* d_in, const int* in_sizes, int n_in,
                              void* d_out, int out_size, void* d_ws, size_t ws_size,
                              hipStream_t stream)
{
    const float* features = (const float*)d_in[0];
    const float* hidden   = (const float*)d_in[1];
    const float* W1w      = (const float*)d_in[2];
    const float* W1b      = (const float*)d_in[3];
    const float* W2w      = (const float*)d_in[4];
    const float* W2b      = (const float*)d_in[5];
    const float* Vw       = (const float*)d_in[6];
    const float* Vb       = (const float*)d_in[7];

    float* ctx = (float*)d_out;                       // (B,E)
    float* wts = (float*)d_out + (size_t)Bdim * Edim; // (B,F)

    // Workspace layout
    float* cb = (float*)d_ws;                                       // 128 KiB
    unsigned short* W1Th  = (unsigned short*)((char*)d_ws + 131072);
    unsigned short* W1Tl  = W1Th + (size_t)Udim * Edim;
    unsigned short* featB = (unsigned short*)((char*)d_ws + (1 << 20));
    const long nfeat = (long)Bdim * Fdim * Edim;                    // 67,108,864
    const size_t NEED = (size_t)(1 << 20) + (size_t)nfeat * 2;      // ~135 MB

    hipMemsetAsync(ctx, 0, (size_t)Bdim * Edim * sizeof(float), stream);
    proj_h_kernel<<<Bdim, 256, 0, stream>>>(hidden, W2w, W1b, W2b, cb);

    if (ws_size >= NEED) {
        feat2bf_kernel<<<4096, 256, 0, stream>>>(features, featB, nfeat);
        w1t_kernel<<<Edim, 256, 0, stream>>>(W1w, W1Th, W1Tl);
        init_scores_kernel<<<(Bdim * Fdim) / 256, 256, 0, stream>>>(wts, Vb);
        dim3 sgrid(Fdim / 128, Udim / 128, Bdim);   // (32, 4, 64)
        score_mfma_kernel<<<sgrid, 256, 0, stream>>>(featB, W1Th, W1Tl, Vw, cb, wts);
    } else {
        dim3 sgrid(Fdim / TFt, Bdim);
        score_kernel<<<sgrid, 256, 0, stream>>>(features, W1w, Vw, Vb, cb, wts);
    }

    softmax_kernel<<<Bdim, 256, 0, stream>>>(wts);

    dim3 cgrid(16, Bdim);
    context_kernel<<<cgrid, 256, 0, stream>>>(features, wts, ctx);
}